// Round 1
// baseline (260.247 us; speedup 1.0000x reference)
//
#include <hip/hip_runtime.h>

// Linear attention: out = (relu(Q)+eps) @ [(relu(K)+eps)^T @ V], per batch.
// B=8, S=4096, D=256, DV=256, fp32 in/out.
// Round 0: fp32 vector baseline. KV via 4-way S-split partials + reduce,
// then out GEMM. Both GEMMs: 64x64 block tile, 4x4 thread tile, float4 LDS.

#define BB   8
#define SS   4096
#define DD   256
#define DDV  256
#define EPSF 1e-6f
#define NCHUNK 4
#define KC   16

// ---------------- Kernel A: KV partials ----------------
// part[chunk][b][d][v] = sum_{k in chunk} (relu(K[b,k,d])+eps) * V[b,k,v]
__global__ __launch_bounds__(256) void kv_partial_kernel(
    const float* __restrict__ K, const float* __restrict__ V,
    float* __restrict__ part) {
  const int tile  = blockIdx.x;   // 0..15 -> (d-tile, v-tile)
  const int chunk = blockIdx.y;   // 0..NCHUNK-1
  const int b     = blockIdx.z;
  const int d0 = (tile >> 2) << 6;
  const int v0 = (tile & 3) << 6;
  const int k0 = chunk * (SS / NCHUNK);

  __shared__ __align__(16) float Kt[KC][64];
  __shared__ __align__(16) float Vt[KC][64];

  const int tid = threadIdx.x;
  const int ty = tid >> 4, tx = tid & 15;
  float acc[4][4] = {};

  const float* Kb = K + (size_t)b * SS * DD  + (size_t)k0 * DD  + d0;
  const float* Vb = V + (size_t)b * SS * DDV + (size_t)k0 * DDV + v0;

  for (int kk = 0; kk < SS / NCHUNK; kk += KC) {
    #pragma unroll
    for (int i = 0; i < 4; i++) {
      int idx = tid + (i << 8);
      int r = idx >> 6, c = idx & 63;
      float kval = Kb[(size_t)(kk + r) * DD + c];
      Kt[r][c] = fmaxf(kval, 0.0f) + EPSF;
      Vt[r][c] = Vb[(size_t)(kk + r) * DDV + c];
    }
    __syncthreads();
    #pragma unroll
    for (int c = 0; c < KC; c++) {
      float4 a4 = *(const float4*)&Kt[c][ty << 2];
      float4 b4 = *(const float4*)&Vt[c][tx << 2];
      float a[4] = {a4.x, a4.y, a4.z, a4.w};
      float bb[4] = {b4.x, b4.y, b4.z, b4.w};
      #pragma unroll
      for (int i = 0; i < 4; i++)
        #pragma unroll
        for (int j = 0; j < 4; j++)
          acc[i][j] += a[i] * bb[j];
    }
    __syncthreads();
  }

  float* p = part + ((size_t)chunk * BB + b) * DD * DDV;
  #pragma unroll
  for (int i = 0; i < 4; i++) {
    int d = d0 + (ty << 2) + i;
    float4 st = make_float4(acc[i][0], acc[i][1], acc[i][2], acc[i][3]);
    *(float4*)&p[(size_t)d * DDV + v0 + (tx << 2)] = st;
  }
}

// ---------------- Kernel R: reduce partials ----------------
__global__ __launch_bounds__(256) void kv_reduce_kernel(
    const float* __restrict__ part, float* __restrict__ kv) {
  const size_t N = (size_t)BB * DD * DDV;
  size_t i = (size_t)blockIdx.x * blockDim.x + threadIdx.x;
  if (i < N) {
    float s = 0.0f;
    #pragma unroll
    for (int c = 0; c < NCHUNK; c++) s += part[(size_t)c * N + i];
    kv[i] = s;
  }
}

// ---------------- Kernel B: out = (relu(Q)+eps) @ KV ----------------
__global__ __launch_bounds__(256) void out_kernel(
    const float* __restrict__ Q, const float* __restrict__ KV,
    float* __restrict__ out) {
  const int vt = blockIdx.x;   // 0..3
  const int qt = blockIdx.y;   // 0..63
  const int b  = blockIdx.z;
  const int q0 = qt << 6, v0 = vt << 6;

  // Qs padded to 68 floats/row: row stride 272B (16B-aligned for float4
  // reads, 4c+q bank pattern on write -> only 2-way aliasing, free).
  __shared__ __align__(16) float Qs[KC][68];
  __shared__ __align__(16) float KVs[KC][64];

  const int tid = threadIdx.x;
  const int ty = tid >> 4, tx = tid & 15;
  float acc[4][4] = {};

  const float* Qb  = Q  + (size_t)b * SS * DD + (size_t)q0 * DD;
  const float* KVb = KV + (size_t)b * DD * DDV + v0;

  for (int dc = 0; dc < DD; dc += KC) {
    #pragma unroll
    for (int i = 0; i < 4; i++) {
      int idx = tid + (i << 8);
      // Q tile: 64 q-rows x 16 d-cols, stored transposed Qs[c][qrow]
      int qrow = idx >> 4, c = idx & 15;
      float qv = Qb[(size_t)qrow * DD + dc + c];
      Qs[c][qrow] = fmaxf(qv, 0.0f) + EPSF;
      // KV tile: 16 d-rows x 64 v-cols
      int r = idx >> 6, vcol = idx & 63;
      KVs[r][vcol] = KVb[(size_t)(dc + r) * DDV + vcol];
    }
    __syncthreads();
    #pragma unroll
    for (int c = 0; c < KC; c++) {
      float4 a4 = *(const float4*)&Qs[c][ty << 2];
      float4 b4 = *(const float4*)&KVs[c][tx << 2];
      float a[4] = {a4.x, a4.y, a4.z, a4.w};
      float bb[4] = {b4.x, b4.y, b4.z, b4.w};
      #pragma unroll
      for (int i = 0; i < 4; i++)
        #pragma unroll
        for (int j = 0; j < 4; j++)
          acc[i][j] += a[i] * bb[j];
    }
    __syncthreads();
  }

  float* ob = out + (size_t)b * SS * DDV + (size_t)q0 * DDV + v0;
  #pragma unroll
  for (int i = 0; i < 4; i++) {
    float4 st = make_float4(acc[i][0], acc[i][1], acc[i][2], acc[i][3]);
    *(float4*)&ob[(size_t)((ty << 2) + i) * DDV + (tx << 2)] = st;
  }
}

extern "C" void kernel_launch(void* const* d_in, const int* in_sizes, int n_in,
                              void* d_out, int out_size, void* d_ws, size_t ws_size,
                              hipStream_t stream) {
  const float* Q = (const float*)d_in[0];
  const float* K = (const float*)d_in[1];
  const float* V = (const float*)d_in[2];
  float* out = (float*)d_out;

  // ws layout: [NCHUNK partials: NCHUNK*B*D*DV floats][kv: B*D*DV floats]
  float* part = (float*)d_ws;
  float* kv   = part + (size_t)NCHUNK * BB * DD * DDV;

  kv_partial_kernel<<<dim3(16, NCHUNK, BB), 256, 0, stream>>>(K, V, part);
  kv_reduce_kernel<<<dim3((BB * DD * DDV) / 256), 256, 0, stream>>>(part, kv);
  out_kernel<<<dim3(4, 64, BB), 256, 0, stream>>>(Q, kv, out);
}

// Round 2
// 154.063 us; speedup vs baseline: 1.6892x; 1.6892x over previous
//
#include <hip/hip_runtime.h>

// Linear attention via bf16 MFMA:
//   KVT[b][v][d] = sum_k V[b,k,v] * (relu(K[b,k,d])+eps)   (fp32 partials over S-chunks)
//   out[b][q,v]  = sum_d (relu(Q[b,q,d])+eps) * KVT[b][v][d]
// All GEMMs use mfma_f32_16x16x32_bf16. LDS tiles are [row][k] with k contiguous
// (ds_read_b128 fragments) and 16B-chunk XOR swizzle (chunk ^= row&7) so both the
// transposed staging writes and the fragment reads run at the bank-conflict floor.

#define BB 8
#define SS 4096
#define DD 256
#define DDV 256
#define EPSF 1e-6f

typedef short bf16x8 __attribute__((ext_vector_type(8)));
typedef float f32x4 __attribute__((ext_vector_type(4)));

__device__ __forceinline__ unsigned int f2bf(float f) {
  unsigned int u = __float_as_uint(f);
  u += 0x7FFF + ((u >> 16) & 1);   // RNE
  return u >> 16;
}
__device__ __forceinline__ unsigned int pack2(float a, float b) {
  return f2bf(a) | (f2bf(b) << 16);
}

// ---------------- Kernel A: KVT partials ----------------
// grid (2 /*v-tile*/, NCHUNK, BB), block 512. Tile: 128 v x 256 d, BK=64.
__global__ __launch_bounds__(512) void kvt_kernel(
    const float* __restrict__ K, const float* __restrict__ V,
    float* __restrict__ part, int kchunk) {
  const int vt    = blockIdx.x;
  const int chunk = blockIdx.y;
  const int b     = blockIdx.z;
  const int k0blk = chunk * kchunk;

  __shared__ ushort Vt[128 * 64];  // [v][k] swizzled, 16 KB
  __shared__ ushort Kt[256 * 64];  // [d][k] swizzled, 32 KB

  const int tid  = threadIdx.x;
  const int lane = tid & 63;
  const int w    = tid >> 6;   // 0..7
  const int wv   = w >> 2;     // 0..1 (v dir)
  const int wd   = w & 3;      // 0..3 (d dir)

  f32x4 acc[4][4];
  #pragma unroll
  for (int i = 0; i < 4; i++)
    #pragma unroll
    for (int j = 0; j < 4; j++)
      acc[i][j] = (f32x4){0.f, 0.f, 0.f, 0.f};

  const float* Vb = V + (size_t)b * SS * DDV + vt * 128;
  const float* Kb = K + (size_t)b * SS * DD;

  for (int kk = 0; kk < kchunk; kk += 64) {
    // ---- stage V tile: 128 rows (v) x 8 octets, transpose via 8 scalar rounds ----
    {
      const int r = tid & 127;
      const int ob = tid >> 7;   // 0..3
      #pragma unroll
      for (int p = 0; p < 2; p++) {
        const int o = ob + p * 4;
        float f[8];
        #pragma unroll
        for (int j = 0; j < 8; j++)
          f[j] = Vb[(size_t)(k0blk + kk + o * 8 + j) * DDV + r];
        uint4 wqv;
        wqv.x = pack2(f[0], f[1]); wqv.y = pack2(f[2], f[3]);
        wqv.z = pack2(f[4], f[5]); wqv.w = pack2(f[6], f[7]);
        const int co = o ^ (r & 7);
        *(uint4*)&Vt[r * 64 + co * 8] = wqv;
      }
    }
    // ---- stage K tile: 256 rows (d) x 8 octets ----
    {
      const int r = tid & 255;
      const int ob = tid >> 8;   // 0..1
      #pragma unroll
      for (int p = 0; p < 4; p++) {
        const int o = ob + p * 2;
        float f[8];
        #pragma unroll
        for (int j = 0; j < 8; j++)
          f[j] = Kb[(size_t)(k0blk + kk + o * 8 + j) * DD + r];
        #pragma unroll
        for (int j = 0; j < 8; j++) f[j] = fmaxf(f[j], 0.0f) + EPSF;
        uint4 wqk;
        wqk.x = pack2(f[0], f[1]); wqk.y = pack2(f[2], f[3]);
        wqk.z = pack2(f[4], f[5]); wqk.w = pack2(f[6], f[7]);
        const int co = o ^ (r & 7);
        *(uint4*)&Kt[r * 64 + co * 8] = wqk;
      }
    }
    __syncthreads();
    // ---- MFMA: 2 k-steps of 32 ----
    #pragma unroll
    for (int ks = 0; ks < 2; ks++) {
      const int oct = ks * 4 + (lane >> 4);
      bf16x8 af[4], bfr[4];
      #pragma unroll
      for (int i = 0; i < 4; i++) {
        const int row = wv * 64 + i * 16 + (lane & 15);
        af[i] = *(const bf16x8*)&Vt[row * 64 + (oct ^ (row & 7)) * 8];
      }
      #pragma unroll
      for (int j = 0; j < 4; j++) {
        const int row = wd * 64 + j * 16 + (lane & 15);
        bfr[j] = *(const bf16x8*)&Kt[row * 64 + (oct ^ (row & 7)) * 8];
      }
      #pragma unroll
      for (int i = 0; i < 4; i++)
        #pragma unroll
        for (int j = 0; j < 4; j++)
          acc[i][j] = __builtin_amdgcn_mfma_f32_16x16x32_bf16(af[i], bfr[j], acc[i][j], 0, 0, 0);
    }
    __syncthreads();
  }

  // epilogue: fp32 partial store, KVT layout [v][d]
  float* pb = part + ((size_t)chunk * BB + b) * (DD * DDV);
  #pragma unroll
  for (int i = 0; i < 4; i++) {
    const int v = vt * 128 + wv * 64 + i * 16 + ((lane >> 4) << 2);
    #pragma unroll
    for (int j = 0; j < 4; j++) {
      const int d = wd * 64 + j * 16 + (lane & 15);
      #pragma unroll
      for (int r = 0; r < 4; r++)
        pb[(size_t)(v + r) * DD + d] = acc[i][j][r];
    }
  }
}

// ---------------- Kernel R: reduce partials -> bf16 KVT ----------------
// grid 512, block 256; each thread: 4 consecutive d.
__global__ __launch_bounds__(256) void reduce_kernel(
    const float* __restrict__ part, ushort* __restrict__ kvb, int nchunk) {
  const size_t N = (size_t)BB * DD * DDV;        // 524288
  const size_t i4 = ((size_t)blockIdx.x * 256 + threadIdx.x) * 4;
  float4 s = make_float4(0.f, 0.f, 0.f, 0.f);
  for (int c = 0; c < nchunk; c++) {
    float4 p = *(const float4*)&part[(size_t)c * N + i4];
    s.x += p.x; s.y += p.y; s.z += p.z; s.w += p.w;
  }
  uint2 o;
  o.x = pack2(s.x, s.y);
  o.y = pack2(s.z, s.w);
  *(uint2*)&kvb[i4] = o;
}

// ---------------- Kernel B: out = (relu(Q)+eps) @ KVT^T ----------------
// grid (32 /*q-tile*/, BB), block 512. Tile: 128 q x 256 v, BK=64 over d.
__global__ __launch_bounds__(512) void out_kernel(
    const float* __restrict__ Q, const ushort* __restrict__ kvb,
    float* __restrict__ out) {
  const int qt = blockIdx.x;
  const int b  = blockIdx.y;
  const int q0 = qt * 128;

  __shared__ ushort Qs[128 * 64];   // [q][d] swizzled, 16 KB
  __shared__ ushort KVs[256 * 64];  // [v][d] swizzled, 32 KB

  const int tid  = threadIdx.x;
  const int lane = tid & 63;
  const int w    = tid >> 6;
  const int wq_  = w >> 2;   // 0..1 (q dir)
  const int wv_  = w & 3;    // 0..3 (v dir)

  f32x4 acc[4][4];
  #pragma unroll
  for (int i = 0; i < 4; i++)
    #pragma unroll
    for (int j = 0; j < 4; j++)
      acc[i][j] = (f32x4){0.f, 0.f, 0.f, 0.f};

  const float* Qb = Q + ((size_t)b * SS + q0) * DD;
  const ushort* KVb = kvb + (size_t)b * DD * DDV;

  for (int dc = 0; dc < DD; dc += 64) {
    // ---- stage Q: 128 q x 64 d, float4 loads, relu+eps+cvt ----
    {
      const int dq = tid & 15;
      int q = tid >> 4;          // 0..31
      #pragma unroll
      for (int p = 0; p < 4; p++, q += 32) {
        float4 f = *(const float4*)&Qb[(size_t)q * DD + dc + dq * 4];
        f.x = fmaxf(f.x, 0.f) + EPSF; f.y = fmaxf(f.y, 0.f) + EPSF;
        f.z = fmaxf(f.z, 0.f) + EPSF; f.w = fmaxf(f.w, 0.f) + EPSF;
        uint2 wp; wp.x = pack2(f.x, f.y); wp.y = pack2(f.z, f.w);
        const int addr = q * 64 + (((dq >> 1) ^ (q & 7)) << 3) + ((dq & 1) << 2);
        *(uint2*)&Qs[addr] = wp;
      }
    }
    // ---- stage KV: 256 v x 64 d bf16, 16B chunks (source-permuted for swizzle) ----
    {
      const int c = tid & 7;
      int row = tid >> 3;        // 0..63
      #pragma unroll
      for (int p = 0; p < 4; p++, row += 64) {
        const int o = c ^ (row & 7);
        uint4 val = *(const uint4*)&KVb[(size_t)row * DD + dc + o * 8];
        *(uint4*)&KVs[row * 64 + c * 8] = val;
      }
    }
    __syncthreads();
    #pragma unroll
    for (int ks = 0; ks < 2; ks++) {
      const int oct = (dc >> 3) + ks * 4 + (lane >> 4);
      const int octl = oct & 7;  // oct within current BK tile
      bf16x8 af[4], bfr[4];
      #pragma unroll
      for (int i = 0; i < 4; i++) {
        const int row = wq_ * 64 + i * 16 + (lane & 15);
        af[i] = *(const bf16x8*)&Qs[row * 64 + (octl ^ (row & 7)) * 8];
      }
      #pragma unroll
      for (int j = 0; j < 4; j++) {
        const int row = wv_ * 64 + j * 16 + (lane & 15);
        bfr[j] = *(const bf16x8*)&KVs[row * 64 + (octl ^ (row & 7)) * 8];
      }
      #pragma unroll
      for (int i = 0; i < 4; i++)
        #pragma unroll
        for (int j = 0; j < 4; j++)
          acc[i][j] = __builtin_amdgcn_mfma_f32_16x16x32_bf16(af[i], bfr[j], acc[i][j], 0, 0, 0);
    }
    __syncthreads();
  }

  float* ob = out + ((size_t)b * SS + q0) * DDV;
  #pragma unroll
  for (int i = 0; i < 4; i++) {
    const int qrow = wq_ * 64 + i * 16 + ((lane >> 4) << 2);
    #pragma unroll
    for (int j = 0; j < 4; j++) {
      const int v = wv_ * 64 + j * 16 + (lane & 15);
      #pragma unroll
      for (int r = 0; r < 4; r++)
        ob[(size_t)(qrow + r) * DDV + v] = acc[i][j][r];
    }
  }
}

extern "C" void kernel_launch(void* const* d_in, const int* in_sizes, int n_in,
                              void* d_out, int out_size, void* d_ws, size_t ws_size,
                              hipStream_t stream) {
  const float* Q = (const float*)d_in[0];
  const float* K = (const float*)d_in[1];
  const float* V = (const float*)d_in[2];
  float* out = (float*)d_out;

  const size_t N = (size_t)BB * DD * DDV;  // 524288 elements
  // ws: [nchunk fp32 partials][bf16 KVT]
  int nchunk = 16;
  while (nchunk > 1 && (size_t)nchunk * N * 4 + N * 2 > ws_size) nchunk >>= 1;
  const int kchunk = SS / nchunk;

  float* part = (float*)d_ws;
  ushort* kvb = (ushort*)(part + (size_t)nchunk * N);

  kvt_kernel<<<dim3(2, nchunk, BB), 512, 0, stream>>>(K, V, part, kchunk);
  reduce_kernel<<<dim3(512), 256, 0, stream>>>(part, kvb, nchunk);
  out_kernel<<<dim3(32, BB), 512, 0, stream>>>(Q, kvb, out);
}